// Round 1
// baseline (168.665 us; speedup 1.0000x reference)
//
#include <hip/hip_runtime.h>
#include <math.h>

#define BATCH  32
#define CH     3
#define H      512
#define W      512
#define KWIN   15
#define PAD    7
#define TH     16                 // output rows per wave
#define NRR    (TH + KWIN - 1)    // 30 input rows per wave
#define STRIP  240                // output cols per wave (frame = 256 cols)
#define NSTRIP 3                  // 240 + 240 + 32
#define NWAVES (BATCH * (H / TH) * NSTRIP)   // 3072 -> 768 blocks = 3/CU, tail-free
#define DEPTH  4                  // software-pipeline depth (rows of loads in flight)

static __device__ __forceinline__ float4 min4(float4 a, float4 b) {
    float4 r;
    r.x = fminf(a.x, b.x);
    r.y = fminf(a.y, b.y);
    r.z = fminf(a.z, b.z);
    r.w = fminf(a.w, b.w);
    return r;
}

// R17: same fused dark-channel + 15x15 min-pool structure as dcp_fused8
// (best 159.2 us bench / ~55 us kernel), but lane width 2 -> 4 cols via b128
// (float4) loads. Rationale: kernel is latency/concurrency-bound (HBM 2.2/6.3
// TB/s, L2 4/34, VALU 10% -- nothing saturated); prior rounds scaled load
// COUNT (DEPTH 2->5: +1.5%) and wave count (TH=8: nil) but never BYTES PER
// LOAD SLOT. b64 -> b128 doubles bytes per outstanding-request slot (512B ->
// 1KB per wave-instr), the axis the 6.8 TB/s fill kernels exploit.
// Also: 768 blocks = exactly 3 blocks/CU -> no ragged dispatch tail
// (dcp_fused8's 1280 blocks at 4/CU ran 1024+256).
// DO NOT (carried from prior session): __launch_bounds__ (VGPR squeeze ->
// serialization/spill), arrays with non-constant indexing after unroll
// (lowers to scratch/LDS), channel-min as separate pass (+5-7 us), TH=32
// (unroll failure), TH=8 (no gain).
__global__ void dcp_fused9(const float* __restrict__ I, float* __restrict__ out) {
    const int wid = blockIdx.x * 4 + (threadIdx.x >> 6);
    const int L   = threadIdx.x & 63;
    const int s   = wid % NSTRIP;
    const int rb  = (wid / NSTRIP) % (H / TH);
    const int b   = wid / (NSTRIP * (H / TH));
    const int y0  = rb * TH;
    const int f   = s * STRIP - 8 + 4 * L;            // frame col (multiple of 4)
    const int cl  = min(max(f, 0), W - 4);            // clamped, keeps 16B alignment
    const bool cv = (f >= 0) && (f < W);              // all-4-cols validity is lane-uniform
    const bool st = (L >= 2) && (L <= 61) && (f <= W - 4); // lane stores 4 output cols

    const float* base = I + (size_t)b * CH * H * W + cl;
    float* outb = out + (size_t)b * H * W;

    // flat step q -> h-min row index: 15..29 (P-build), then 14..0 (U-stream)
    auto seqrow = [](int q) { return q < KWIN ? KWIN + q : 29 - q; };

    auto loadrow = [&](int i, float4& A, float4& B, float4& C) {
        const int yc = min(max(y0 - PAD + i, 0), H - 1);
        const float* p = base + (size_t)yc * W;
        A = *(const float4*)(p);
        B = *(const float4*)(p + (size_t)H * W);
        C = *(const float4*)(p + (size_t)2 * H * W);
    };

    // lane holds frame cols f..f+3; output col f+j needs window [f+j-7, f+j+7]
    auto hcompute = [&](int i, float4 A, float4 B, float4 C) -> float4 {
        const int y = y0 - PAD + i;
        float4 d = min4(min4(A, B), C);
        const bool pad = (y < 0) || (y >= H) || !cv;
        d.x = pad ? INFINITY : d.x;                   // select, not branch
        d.y = pad ? INFINITY : d.y;
        d.z = pad ? INFINITY : d.z;
        d.w = pad ? INFINITY : d.w;
        const float p01  = fminf(d.x, d.y);
        const float p23  = fminf(d.z, d.w);
        const float m    = fminf(p01, p23);           // min cols f..f+3
        const float pre3 = fminf(p01, d.z);           // min cols f..f+2
        const float suf3 = fminf(d.y, p23);           // min cols f+1..f+3
        const float mL   = __shfl_up(m, 1);           // cols f-4..f-1
        const float mR   = __shfl_down(m, 1);         // cols f+4..f+7
        const float cmn  = fminf(fminf(mL, mR), m);   // cols f-4..f+7 (12 cols)
        const float s1   = __shfl_up(d.w, 2);         // col  f-5
        const float s2   = __shfl_up(p23, 2);         // cols f-6..f-5
        const float s3   = __shfl_up(suf3, 2);        // cols f-7..f-5
        const float q1   = __shfl_down(d.x, 2);       // col  f+8
        const float q2   = __shfl_down(p01, 2);       // cols f+8..f+9
        const float q3   = __shfl_down(pre3, 2);      // cols f+8..f+10
        float4 wv;
        wv.x = fminf(cmn, s3);                        // [f-7 .. f+7]
        wv.y = fminf(fminf(s2, q1), cmn);             // [f-6 .. f+8]
        wv.z = fminf(fminf(s1, q2), cmn);             // [f-5 .. f+9]
        wv.w = fminf(cmn, q3);                        // [f-4 .. f+10]
        return wv;
    };

    float4 Ab[DEPTH], Bb[DEPTH], Cb[DEPTH];
    #pragma unroll
    for (int j = 0; j < DEPTH; ++j)
        loadrow(seqrow(j), Ab[j], Bb[j], Cb[j]);      // 12 b128 loads issued up front

    float4 P[KWIN];
    float4 U;
    #pragma unroll
    for (int q = 0; q < NRR; ++q) {
        const int sl = q % DEPTH;                     // constant-folded (unrolled)
        const float4 h = hcompute(seqrow(q), Ab[sl], Bb[sl], Cb[sl]);
        if (q + DEPTH < NRR)
            loadrow(seqrow(q + DEPTH), Ab[sl], Bb[sl], Cb[sl]);

        if (q == 0) {
            P[0] = h;
        } else if (q < KWIN) {
            P[q] = min4(P[q - 1], h);                 // P[q] = min(rows 15..15+q)
            if (q == KWIN - 1 && st)
                *(float4*)(outb + (size_t)(y0 + 15) * W + f) = P[KWIN - 1];
        } else if (q == KWIN) {                       // row 14
            U = h;
            if (st) *(float4*)(outb + (size_t)(y0 + 14) * W + f) = min4(U, P[13]);
        } else if (q < NRR - 1) {                     // rows 13..1
            const int r = 29 - q;
            U = min4(U, h);
            if (st) *(float4*)(outb + (size_t)(y0 + r) * W + f) = min4(U, P[r - 1]);
        } else {                                      // row 0
            U = min4(U, h);
            if (st) *(float4*)(outb + (size_t)y0 * W + f) = U;
        }
    }
}

extern "C" void kernel_launch(void* const* d_in, const int* in_sizes, int n_in,
                              void* d_out, int out_size, void* d_ws, size_t ws_size,
                              hipStream_t stream) {
    const float* I = (const float*)d_in[0];
    // d_in[1] is k == 15, hard-coded (KWIN/PAD)
    float* out = (float*)d_out;
    dcp_fused9<<<dim3(NWAVES / 4), dim3(256), 0, stream>>>(I, out);
}

// Round 3
// 159.757 us; speedup vs baseline: 1.0558x; 1.0558x over previous
//
#include <hip/hip_runtime.h>
#include <math.h>

#define BATCH  32
#define CH     3
#define H      512
#define W      512
#define KWIN   15
#define PAD    7
#define TB     64                 // output rows per BLOCK (4 waves x 16 rows)
#define NR     (TB + KWIN - 1)    // 78 staged h-min rows per block
#define STRIP  112                // output cols per block (frame = 128)
#define NSTRIP 5
#define LROW   112                // floats per LDS h-row
#define NBLK   (BATCH * (H / TB) * NSTRIP)   // 32*8*5 = 1280 blocks

static __device__ __forceinline__ float2 min2(float2 a, float2 b) {
    float2 r;
    r.x = fminf(a.x, b.x);
    r.y = fminf(a.y, b.y);
    return r;
}

// R18 (resubmit after broker timeout; never measured). LDS h-min staging.
// Theory: prior structures are bound by ISSUED read bytes through L2/L3
// (~4.3-4.6 TB/s for this pattern; time tracked issued bytes across
// fused8/fused9, not instr count, not occupancy). fused8 issued 236 MB
// (1.875x vertical halo re-read x 1.25x frame waste). Here a 4-wave block
// stages 78 h-min-reduced rows (3ch min + 15-wide h-min, 4 B/col) in 35 KB
// LDS ONCE, then each wave runs vertical van Herk from LDS. Issued global
// reads: 1280 blk * 78 rows * 3ch * 512 B = 153 MB (1.22x vert).
// NOT the same as R11's DO-NOT (that was a global-memory two-pass round-trip);
// single barrier, LDS-local.
// DO NOT (carried): __launch_bounds__ (VGPR squeeze), non-constant array
// indexing after unroll (scratch), global two-pass (R11), TH=32 full-unroll
// van Herk in regs (R13), b128 wasted-frame geometry (R17: 3rd strip 87% waste).
__global__ void dcp_lds1(const float* __restrict__ I, float* __restrict__ out) {
    __shared__ float hl[NR][LROW];                    // 78*112*4 = 34944 B

    const int w   = threadIdx.x >> 6;                 // wave 0..3
    const int L   = threadIdx.x & 63;
    const int bid = blockIdx.x;
    const int s   = bid % NSTRIP;
    const int rg  = (bid / NSTRIP) % (H / TB);        // 0..7
    const int b   = bid / (NSTRIP * (H / TB));
    const int Y0  = rg * TB;                          // first output row of block

    // ---- stage-phase lane geometry (identical to fused8's proven mapping) ----
    const int f   = s * STRIP - 8 + 2 * L;            // frame col (even)
    const int cl  = min(max(f, 0), W - 2);            // clamped, 8B-aligned
    const bool cv = (f >= 0) && (f < W);
    const bool sw = (L >= 4) && (L <= 59);            // lane writes LDS (local cols 2L-8, 2L-7)

    const float* base = I + (size_t)b * CH * H * W + cl;
    float* outb = out + (size_t)b * H * W;

    auto ldrow = [&](int j, float2& A, float2& B, float2& C) {
        const int gc = min(max(Y0 - PAD + j, 0), H - 1);
        const float* p = base + (size_t)gc * W;
        A = *(const float2*)(p);
        B = *(const float2*)(p + (size_t)H * W);
        C = *(const float2*)(p + (size_t)2 * H * W);
    };

    // channel-min + 15-wide horizontal min (verified shuffle net from fused8)
    auto hrow = [&](int j, float2 A, float2 B, float2 C) -> float2 {
        const int g = Y0 - PAD + j;                   // global input row
        float2 d = min2(min2(A, B), C);
        const bool pad = (g < 0) || (g >= H) || !cv;
        d.x = pad ? INFINITY : d.x;                   // select, not branch
        d.y = pad ? INFINITY : d.y;
        const float pm = fminf(d.x, d.y);             // pair min (cols f,f+1)
        const float t2 = fminf(pm, __shfl_down(pm, 1));
        const float t4 = fminf(t2, __shfl_down(t2, 2));
        const float q7 = fminf(t4, __shfl_up(t4, 3)); // cols f-6..f+7
        float2 wv;
        wv.x = fminf(q7, __shfl_up(d.y, 4));          // + col f-7
        wv.y = fminf(q7, __shfl_down(d.x, 4));        // + col f+8
        return wv;
    };

    // ---- phase 1: stage 78 h-min rows, round-robin rows across the 4 waves ----
    // wave w handles rows j = w, w+4, ..., pipelined 4 deep (12 loads in flight)
    float2 Ab[4], Bb[4], Cb[4];
    #pragma unroll
    for (int t = 0; t < 4; ++t)
        ldrow(w + 4 * t, Ab[t], Bb[t], Cb[t]);        // j <= 15 < NR always

    #pragma unroll
    for (int t = 0; t < 20; ++t) {
        const int j = w + 4 * t;
        if (j < NR) {                                 // wave-uniform branch
            const int sl = t & 3;                     // constant after unroll
            const float2 hv = hrow(j, Ab[sl], Bb[sl], Cb[sl]);
            const int j2 = w + 4 * (t + 4);
            if (t + 4 < 20 && j2 < NR)
                ldrow(j2, Ab[sl], Bb[sl], Cb[sl]);
            if (sw)
                *(float2*)&hl[j][2 * L - 8] = hv;     // banks 2L-8 mod 32: 2-way, free
        }
    }
    __syncthreads();

    // ---- phase 2: vertical 15-min van Herk from LDS; wave w -> out rows Y0+16w.. ----
    const int lw = 16 * w;                            // local base row
    const int c  = min(2 * L, LROW - 2);              // local col (clamped for lanes 56..63)
    const int oc = s * STRIP + 2 * L;                 // global out col
    const bool st = (2 * L < LROW) && (oc < W);       // valid store lanes

    auto seqrow = [](int q) { return q < KWIN ? KWIN + q : 29 - q; };
    auto rdrow  = [&](int l) -> float2 {
        return *(const float2*)&hl[lw + l][c];
    };

    float2 P[KWIN];
    float2 U;
    #pragma unroll
    for (int q = 0; q < 30; ++q) {
        const int l = seqrow(q);                      // 15..29 then 14..0
        const float2 h = rdrow(l);
        if (q == 0) {
            P[0] = h;
        } else if (q < KWIN) {
            P[q] = min2(P[q - 1], h);                 // P[q] = min(l=15..15+q)
            if (q == KWIN - 1 && st)
                *(float2*)(outb + (size_t)(Y0 + lw + 15) * W + oc) = P[KWIN - 1];
        } else if (q == KWIN) {                       // l = 14 -> out row 14
            U = h;
            if (st) *(float2*)(outb + (size_t)(Y0 + lw + 14) * W + oc) = min2(U, P[13]);
        } else if (q < 29) {                          // out rows 13..1
            const int r = 29 - q;
            U = min2(U, h);
            if (st) *(float2*)(outb + (size_t)(Y0 + lw + r) * W + oc) = min2(U, P[r - 1]);
        } else {                                      // out row 0
            U = min2(U, h);
            if (st) *(float2*)(outb + (size_t)(Y0 + lw) * W + oc) = U;
        }
    }
}

extern "C" void kernel_launch(void* const* d_in, const int* in_sizes, int n_in,
                              void* d_out, int out_size, void* d_ws, size_t ws_size,
                              hipStream_t stream) {
    const float* I = (const float*)d_in[0];
    // d_in[1] is k == 15, hard-coded (KWIN/PAD)
    float* out = (float*)d_out;
    dcp_lds1<<<dim3(NBLK), dim3(256), 0, stream>>>(I, out);
}

// Round 4
// 159.755 us; speedup vs baseline: 1.0558x; 1.0000x over previous
//
#include <hip/hip_runtime.h>
#include <math.h>

#define BATCH  32
#define CH     3
#define H      512
#define W      512
#define KWIN   15
#define PAD    7
#define TB     64                 // output rows per BLOCK (4 waves x 16 rows)
#define NR     (TB + KWIN - 1)    // 78 staged h-min rows per block
#define STRIP  112                // output cols per block (frame = 128)
#define NSTRIP 5
#define LROW   112                // floats per LDS h-row
#define NBLK   (BATCH * (H / TB) * NSTRIP)   // 32*8*5 = 1280 blocks

static __device__ __forceinline__ float2 min2(float2 a, float2 b) {
    float2 r;
    r.x = fminf(a.x, b.x);
    r.y = fminf(a.y, b.y);
    return r;
}

// R19: dcp_lds1 compute (measured 159.76 us, == fused8) + XCD-grouped block
// swizzle. Measured anomaly: WRITE_SIZE 48.15 MB vs 33.55 ideal = 1.435x,
// matching 256B-sector padding of 448B strip rows (predicted 1.375x). Strips
// of one band currently round-robin across 8 non-coherent XCD L2s -> partial
// lines can't merge. Swizzle: XCD g = bid%8 owns logical ids l in
// [160g,160g+160) = 4 whole images -> all 5 strips of a band are adjacent
// blocks on ONE XCD -> 448B writes merge to full rows in local L2 before
// eviction; vertical band halos (14/78 rows) also hit warm local L2.
// Predict: WRITE 48->~34-38 MB; kernel ~55 -> 48-51 us if traffic binds.
// If WRITE drops and time doesn't: cold-stream ~2.7 TB/s ceiling is real ->
// declare roofline.
// Falsified so far (do not retry): bytes/slot b128 (R17 +10%), issued-bytes
// cut via LDS staging (R18: -34% bytes, 0% time), occupancy 12->16 w/CU (0%),
// VMEM instr count halving (0%), DEPTH/TLP scaling, __launch_bounds__,
// global two-pass, non-constant array indexing after unroll.
__global__ void dcp_lds2(const float* __restrict__ I, float* __restrict__ out) {
    __shared__ float hl[NR][LROW];                    // 78*112*4 = 34944 B

    const int w   = threadIdx.x >> 6;                 // wave 0..3
    const int L   = threadIdx.x & 63;

    // ---- XCD-grouped swizzle: hw bid -> logical work id l (bijective) ----
    // XCD(h)=h%8 owns l in [160*xcd, 160*xcd+160) = images b in [4*xcd,4*xcd+4)
    const int hbid = blockIdx.x;
    const int l    = (hbid & 7) * (NBLK / 8) + (hbid >> 3);
    const int s    = l % NSTRIP;                      // strip fastest: band's 5
    const int Bnd  = l / NSTRIP;                      //  strips adjacent on XCD
    const int rg   = Bnd & 7;                         // band row-group 0..7
    const int b    = Bnd >> 3;                        // image 0..31
    const int Y0   = rg * TB;                         // first output row of block

    // ---- stage-phase lane geometry (proven mapping from fused8/lds1) ----
    const int f   = s * STRIP - 8 + 2 * L;            // frame col (even)
    const int cl  = min(max(f, 0), W - 2);            // clamped, 8B-aligned
    const bool cv = (f >= 0) && (f < W);
    const bool sw = (L >= 4) && (L <= 59);            // lane writes LDS (local cols 2L-8, 2L-7)

    const float* base = I + (size_t)b * CH * H * W + cl;
    float* outb = out + (size_t)b * H * W;

    auto ldrow = [&](int j, float2& A, float2& B, float2& C) {
        const int gc = min(max(Y0 - PAD + j, 0), H - 1);
        const float* p = base + (size_t)gc * W;
        A = *(const float2*)(p);
        B = *(const float2*)(p + (size_t)H * W);
        C = *(const float2*)(p + (size_t)2 * H * W);
    };

    // channel-min + 15-wide horizontal min (verified shuffle net)
    auto hrow = [&](int j, float2 A, float2 B, float2 C) -> float2 {
        const int g = Y0 - PAD + j;                   // global input row
        float2 d = min2(min2(A, B), C);
        const bool pad = (g < 0) || (g >= H) || !cv;
        d.x = pad ? INFINITY : d.x;                   // select, not branch
        d.y = pad ? INFINITY : d.y;
        const float pm = fminf(d.x, d.y);             // pair min (cols f,f+1)
        const float t2 = fminf(pm, __shfl_down(pm, 1));
        const float t4 = fminf(t2, __shfl_down(t2, 2));
        const float q7 = fminf(t4, __shfl_up(t4, 3)); // cols f-6..f+7
        float2 wv;
        wv.x = fminf(q7, __shfl_up(d.y, 4));          // + col f-7
        wv.y = fminf(q7, __shfl_down(d.x, 4));        // + col f+8
        return wv;
    };

    // ---- phase 1: stage 78 h-min rows, round-robin rows across the 4 waves ----
    float2 Ab[4], Bb[4], Cb[4];
    #pragma unroll
    for (int t = 0; t < 4; ++t)
        ldrow(w + 4 * t, Ab[t], Bb[t], Cb[t]);        // j <= 15 < NR always

    #pragma unroll
    for (int t = 0; t < 20; ++t) {
        const int j = w + 4 * t;
        if (j < NR) {                                 // wave-uniform branch
            const int sl = t & 3;                     // constant after unroll
            const float2 hv = hrow(j, Ab[sl], Bb[sl], Cb[sl]);
            const int j2 = w + 4 * (t + 4);
            if (t + 4 < 20 && j2 < NR)
                ldrow(j2, Ab[sl], Bb[sl], Cb[sl]);
            if (sw)
                *(float2*)&hl[j][2 * L - 8] = hv;     // banks 2L-8 mod 32: 2-way, free
        }
    }
    __syncthreads();

    // ---- phase 2: vertical 15-min van Herk from LDS; wave w -> out rows Y0+16w.. ----
    const int lw = 16 * w;                            // local base row
    const int c  = min(2 * L, LROW - 2);              // local col (clamped lanes 56..63)
    const int oc = s * STRIP + 2 * L;                 // global out col
    const bool st = (2 * L < LROW) && (oc < W);       // valid store lanes

    auto seqrow = [](int q) { return q < KWIN ? KWIN + q : 29 - q; };
    auto rdrow  = [&](int lr) -> float2 {
        return *(const float2*)&hl[lw + lr][c];
    };

    float2 P[KWIN];
    float2 U;
    #pragma unroll
    for (int q = 0; q < 30; ++q) {
        const int lr = seqrow(q);                     // 15..29 then 14..0
        const float2 h = rdrow(lr);
        if (q == 0) {
            P[0] = h;
        } else if (q < KWIN) {
            P[q] = min2(P[q - 1], h);                 // P[q] = min(lr=15..15+q)
            if (q == KWIN - 1 && st)
                *(float2*)(outb + (size_t)(Y0 + lw + 15) * W + oc) = P[KWIN - 1];
        } else if (q == KWIN) {                       // lr = 14 -> out row 14
            U = h;
            if (st) *(float2*)(outb + (size_t)(Y0 + lw + 14) * W + oc) = min2(U, P[13]);
        } else if (q < 29) {                          // out rows 13..1
            const int r = 29 - q;
            U = min2(U, h);
            if (st) *(float2*)(outb + (size_t)(Y0 + lw + r) * W + oc) = min2(U, P[r - 1]);
        } else {                                      // out row 0
            U = min2(U, h);
            if (st) *(float2*)(outb + (size_t)(Y0 + lw) * W + oc) = U;
        }
    }
}

extern "C" void kernel_launch(void* const* d_in, const int* in_sizes, int n_in,
                              void* d_out, int out_size, void* d_ws, size_t ws_size,
                              hipStream_t stream) {
    const float* I = (const float*)d_in[0];
    // d_in[1] is k == 15, hard-coded (KWIN/PAD)
    float* out = (float*)d_out;
    dcp_lds2<<<dim3(NBLK), dim3(256), 0, stream>>>(I, out);
}